// Round 3
// baseline (755.375 us; speedup 1.0000x reference)
//
#include <hip/hip_runtime.h>
#include <hip/hip_bf16.h>
#include <stdint.h>

// MoE top-2 (T=8192, D=1024, H=2816, E=8) — sparse grouped-GEMM implementation.
// R3: 256^2 slice-pipelined GEMMs (counted vmcnt, raw barriers, setprio),
//     W13 interleaved weight so gemm1 is single-B with in-register SiLU fusion.

#define T_TOK 8192
#define D_DIM 1024
#define H_DIM 2816
#define E_EXP 8
#define NSLOT 16384       // T * 2
#define CAP_ROWS 18432    // 72 * 256
#define MT2_MAX 72

// meta int layout
#define MI_TOTAL 0
#define MI_CNT 8
#define MI_POS 16
#define MI_MTE 32
#define MI_MTB (32 + MT2_MAX)

typedef __attribute__((ext_vector_type(8))) short short8;
typedef __attribute__((ext_vector_type(4))) float f32x4;

#define GLD16(gsrc, ldst) __builtin_amdgcn_global_load_lds( \
    (const __attribute__((address_space(1))) void*)(gsrc),  \
    (__attribute__((address_space(3))) void*)(ldst), 16, 0, 0)

// ---------------- init ----------------
__global__ __launch_bounds__(64) void init_kernel(int* meta) {
  if (threadIdx.x < E_EXP) meta[MI_CNT + threadIdx.x] = 0;
}

// ---------------- w2 transpose + f32->bf16 ----------------
// in: (E, R, C) f32   out: (E, C, R) bf16.  64x64 tiles, coalesced both sides.
template <int R, int C>
__global__ __launch_bounds__(256) void transpose_convert(const float* __restrict__ in,
                                                         __hip_bfloat16* __restrict__ outp) {
  int e = blockIdx.z;
  int c0 = blockIdx.x * 64, r0 = blockIdx.y * 64;
  __shared__ float tile[64][65];
  int tid = threadIdx.x;
  int lc = (tid & 15) * 4;
  int lr = tid >> 4;
  const float* src = in + ((size_t)e * R + r0) * C + c0;
#pragma unroll
  for (int i = 0; i < 4; i++) {
    float4 v = *(const float4*)(src + (size_t)(lr + i * 16) * C + lc);
    tile[lr + i * 16][lc + 0] = v.x;
    tile[lr + i * 16][lc + 1] = v.y;
    tile[lr + i * 16][lc + 2] = v.z;
    tile[lr + i * 16][lc + 3] = v.w;
  }
  __syncthreads();
  __hip_bfloat16* dst = outp + ((size_t)e * C + c0) * R + r0;
  int rB = (tid & 7) * 8;
#pragma unroll
  for (int i = 0; i < 2; i++) {
    int c = (tid >> 3) + i * 32;
    __align__(16) __hip_bfloat16 o[8];
#pragma unroll
    for (int k = 0; k < 8; k++) o[k] = __float2bfloat16(tile[rB + k][c]);
    *(short8*)(dst + (size_t)c * R + rB) = *(const short8*)o;
  }
}

// ---------------- W13 interleaved transpose ----------------
// w1,w3: (E, D, H) f32 -> w13t: (E, 2H, D) bf16, row(n, which) = 2*(n&~15) + (n&15) + 16*which
__global__ __launch_bounds__(256) void w13_transpose(const float* __restrict__ w1,
                                                     const float* __restrict__ w3,
                                                     __hip_bfloat16* __restrict__ w13t) {
  int z = blockIdx.z;  // 0..2E-1
  int e = z >> 1, w3f = z & 1;
  const float* in = w3f ? w3 : w1;
  int h0 = blockIdx.x * 64, d0 = blockIdx.y * 64;
  __shared__ float tile[64][65];
  int tid = threadIdx.x;
  int lc = (tid & 15) * 4;
  int lr = tid >> 4;
  const float* src = in + ((size_t)e * D_DIM + d0) * H_DIM + h0;
#pragma unroll
  for (int i = 0; i < 4; i++) {
    float4 v = *(const float4*)(src + (size_t)(lr + i * 16) * H_DIM + lc);
    tile[lr + i * 16][lc + 0] = v.x;
    tile[lr + i * 16][lc + 1] = v.y;
    tile[lr + i * 16][lc + 2] = v.z;
    tile[lr + i * 16][lc + 3] = v.w;
  }
  __syncthreads();
  __hip_bfloat16* dstE = w13t + (size_t)e * (2 * H_DIM) * D_DIM;
  int rB = (tid & 7) * 8;  // d offset within tile
#pragma unroll
  for (int i = 0; i < 2; i++) {
    int hh = (tid >> 3) + i * 32;
    int habs = h0 + hh;
    int rw = 2 * (habs & ~15) + (habs & 15) + (w3f ? 16 : 0);
    __align__(16) __hip_bfloat16 o[8];
#pragma unroll
    for (int k = 0; k < 8; k++) o[k] = __float2bfloat16(tile[rB + k][hh]);
    *(short8*)(dstE + (size_t)rw * D_DIM + d0 + rB) = *(const short8*)o;
  }
}

// ---------------- router ----------------
__global__ __launch_bounds__(256) void router_kernel(const float* __restrict__ x,
                                                     const float* __restrict__ Wr,
                                                     int* __restrict__ meta,
                                                     float* __restrict__ Pbuf,
                                                     int* __restrict__ expert_sel,
                                                     float* __restrict__ slot_w) {
  int wave = threadIdx.x >> 6, lane = threadIdx.x & 63;
  int tok = blockIdx.x * 4 + wave;
  const float* xr = x + (size_t)tok * D_DIM;
  float acc[8];
#pragma unroll
  for (int e = 0; e < 8; e++) acc[e] = 0.f;
  for (int d = lane; d < D_DIM; d += 64) {
    float xv = xr[d];
    const float4* w4 = (const float4*)(Wr + d * 8);
    float4 wa = w4[0], wb = w4[1];
    acc[0] += xv * wa.x; acc[1] += xv * wa.y; acc[2] += xv * wa.z; acc[3] += xv * wa.w;
    acc[4] += xv * wb.x; acc[5] += xv * wb.y; acc[6] += xv * wb.z; acc[7] += xv * wb.w;
  }
#pragma unroll
  for (int e = 0; e < 8; e++) {
#pragma unroll
    for (int off = 32; off >= 1; off >>= 1) acc[e] += __shfl_xor(acc[e], off);
  }
  float mx = acc[0];
#pragma unroll
  for (int e = 1; e < 8; e++) mx = fmaxf(mx, acc[e]);
  float p[8], s = 0.f;
#pragma unroll
  for (int e = 0; e < 8; e++) { p[e] = expf(acc[e] - mx); s += p[e]; }
  float inv = 1.f / s;
#pragma unroll
  for (int e = 0; e < 8; e++) p[e] *= inv;
  int i0 = 0;
#pragma unroll
  for (int e = 1; e < 8; e++) if (p[e] > p[i0]) i0 = e;
  int i1 = (i0 == 0) ? 1 : 0;
#pragma unroll
  for (int e = 0; e < 8; e++) if (e != i0 && p[e] > p[i1]) i1 = e;
  float wsum = p[i0] + p[i1];

  __shared__ float sP[4][8];
  if (lane == 0) {
    expert_sel[tok * 2] = i0;
    expert_sel[tok * 2 + 1] = i1;
    slot_w[tok * 2] = p[i0] / wsum;
    slot_w[tok * 2 + 1] = p[i1] / wsum;
    atomicAdd(&meta[MI_CNT + i0], 1);
    atomicAdd(&meta[MI_CNT + i1], 1);
#pragma unroll
    for (int e = 0; e < 8; e++) sP[wave][e] = p[e];
  }
  __syncthreads();
  if (threadIdx.x < 8)
    Pbuf[threadIdx.x * 2048 + blockIdx.x] =
        sP[0][threadIdx.x] + sP[1][threadIdx.x] + sP[2][threadIdx.x] + sP[3][threadIdx.x];
}

// ---------------- offsets + aux loss (256-row segment padding) ----------------
__global__ __launch_bounds__(256) void offsets_kernel(int* __restrict__ meta,
                                                      const float* __restrict__ Pbuf,
                                                      float* __restrict__ aux_out) {
  __shared__ float red[8][33];
  int t = threadIdx.x;
  int e = t >> 5, j = t & 31;
  float s = 0.f;
  for (int c = j; c < 2048; c += 32) s += Pbuf[e * 2048 + c];
  red[e][j] = s;
  __syncthreads();
  if (t == 0) {
    float psum[8];
    for (int ee = 0; ee < 8; ee++) {
      float ss = 0.f;
      for (int k = 0; k < 32; k++) ss += red[ee][k];
      psum[ee] = ss;
    }
    int off = 0, nt = 0;
    float aux = 0.f;
    for (int ee = 0; ee < 8; ee++) {
      int c = meta[MI_CNT + ee];
      meta[MI_POS + ee] = off;
      int tiles = (c + 255) >> 8;
      for (int jj = 0; jj < tiles; jj++) { meta[MI_MTE + nt] = ee; meta[MI_MTB + nt] = off + jj * 256; nt++; }
      off += tiles * 256;
      aux += ((float)c / 16384.f) * (psum[ee] / 8192.f);
    }
    meta[MI_TOTAL] = nt;
    *aux_out = 8.f * aux;
  }
}

// ---------------- assign: ballot-aggregated positions ----------------
__global__ __launch_bounds__(256) void assign_kernel(const int* __restrict__ expert_sel,
                                                     int* __restrict__ meta,
                                                     int* __restrict__ slot_pos) {
  int tid = threadIdx.x, wave = tid >> 6, lane = tid & 63;
  int slot = blockIdx.x * 256 + tid;
  int e = expert_sel[slot];
  __shared__ int cnt[4][8];
  __shared__ int base[8];
  __shared__ int woff[4][8];
  int rank = 0;
#pragma unroll
  for (int ee = 0; ee < 8; ee++) {
    unsigned long long msk = __ballot(e == ee);
    if (lane == 0) cnt[wave][ee] = __popcll(msk);
    if (e == ee) rank = __popcll(msk & ((1ull << lane) - 1ull));
  }
  __syncthreads();
  if (tid < 8) {
    int c0 = cnt[0][tid], c1 = cnt[1][tid], c2 = cnt[2][tid], c3 = cnt[3][tid];
    int tot = c0 + c1 + c2 + c3;
    base[tid] = atomicAdd(&meta[MI_POS + tid], tot);
    woff[0][tid] = 0; woff[1][tid] = c0; woff[2][tid] = c0 + c1; woff[3][tid] = c0 + c1 + c2;
  }
  __syncthreads();
  slot_pos[slot] = base[e] + woff[wave][e] + rank;
}

// ---------------- gather x rows as bf16 ----------------
__global__ __launch_bounds__(256) void gather_kernel(const int* __restrict__ slot_pos,
                                                     const float* __restrict__ x,
                                                     __hip_bfloat16* __restrict__ Xg) {
  int wave = threadIdx.x >> 6, lane = threadIdx.x & 63;
  int slot = blockIdx.x * 4 + wave;
  int pos = slot_pos[slot];
  int tok = slot >> 1;
  const float4* src = (const float4*)(x + (size_t)tok * D_DIM);
  __hip_bfloat16* dst = Xg + (size_t)pos * D_DIM;
#pragma unroll
  for (int p = 0; p < 4; p++) {
    float4 v = src[p * 64 + lane];
    union { ushort4 u4; __hip_bfloat16 h[4]; } cv;
    cv.h[0] = __float2bfloat16(v.x);
    cv.h[1] = __float2bfloat16(v.y);
    cv.h[2] = __float2bfloat16(v.z);
    cv.h[3] = __float2bfloat16(v.w);
    *(ushort4*)(dst + (p * 64 + lane) * 4) = cv.u4;
  }
}

// bijective XCD-chunked swizzle; m fastest within chunk
__device__ __forceinline__ void tile_from_bid(int bid, int nwg, int mmax, int* m, int* n) {
  int cpx = nwg >> 3;
  int u = (bid & 7) * cpx + (bid >> 3);
  *n = u / mmax;
  *m = u % mmax;
}

// =====================================================================
// Slice-pipelined 256-wide GEMMs. K consumed in 32-col slices; 4 LDS
// slice buffers; stage slice g+2 while computing slice g; counted vmcnt.
// LDS tile rows: 64 B pitch, 16B granule swizzle g ^= (row>>1)&3.
// =====================================================================

#define G_PHASE(gg, VMLIT, DOSTAGE, NFRAG, SLICE_BYTES, BOFF)                    \
  {                                                                              \
    if (DOSTAGE) stage((gg) + 2);                                                \
    asm volatile("s_waitcnt vmcnt(" VMLIT ")" ::: "memory");                     \
    __builtin_amdgcn_s_barrier();                                                \
    asm volatile("" ::: "memory");                                               \
    const char* Abuf = lds + ((gg) & 3) * (SLICE_BYTES);                         \
    const char* Bbuf = Abuf + (BOFF);                                            \
    short8 a[8], b[NFRAG];                                                       \
    _Pragma("unroll")                                                            \
    for (int f = 0; f < 8; f++) {                                                \
      int r = wr * 128 + f * 16 + rsel;                                          \
      a[f] = *(const short8*)(Abuf + (r << 6) + ((kg ^ ((r >> 1) & 3)) << 4));   \
    }                                                                            \
    _Pragma("unroll")                                                            \
    for (int f = 0; f < NFRAG; f++) {                                            \
      int r = wc * (16 * NFRAG) + f * 16 + rsel;                                 \
      b[f] = *(const short8*)(Bbuf + (r << 6) + ((kg ^ ((r >> 1) & 3)) << 4));   \
    }                                                                            \
    __builtin_amdgcn_s_setprio(1);                                               \
    _Pragma("unroll")                                                            \
    for (int fm = 0; fm < 8; fm++)                                               \
      _Pragma("unroll")                                                          \
      for (int fn = 0; fn < NFRAG; fn++)                                         \
        acc[fm][fn] = __builtin_amdgcn_mfma_f32_16x16x32_bf16(a[fm], b[fn], acc[fm][fn], 0, 0, 0); \
    __builtin_amdgcn_s_setprio(0);                                               \
    asm volatile("" ::: "memory");                                               \
    __builtin_amdgcn_s_barrier();                                                \
  }

// ---------------- GEMM1: Hb = silu/fuse( Xg @ w13t^T ), 256x256 tile ----------------
__global__ __launch_bounds__(512, 2) void gemm1_kernel(const __hip_bfloat16* __restrict__ Xg,
                                                       const __hip_bfloat16* __restrict__ w13t,
                                                       __hip_bfloat16* __restrict__ Hb,
                                                       const int* __restrict__ meta) {
  int m, nIdx;
  tile_from_bid(blockIdx.x, (2 * H_DIM / 256) * MT2_MAX, MT2_MAX, &m, &nIdx);
  if (m >= meta[MI_TOTAL]) return;
  int e = meta[MI_MTE + m];
  int row0 = meta[MI_MTB + m];
  int n0 = nIdx * 256;
  __shared__ __align__(16) char lds[131072];  // 4 slices x (A 16KB + B 16KB)
  const int tid = threadIdx.x, wid = tid >> 6, lane = tid & 63;
  const int wr = wid >> 2, wc = wid & 3, rsel = lane & 15, kg = lane >> 4;
  const __hip_bfloat16* Ab = Xg + (size_t)row0 * D_DIM;
  const __hip_bfloat16* Bb = w13t + ((size_t)e * (2 * H_DIM) + n0) * D_DIM;

  f32x4 acc[8][4];
#pragma unroll
  for (int i = 0; i < 8; i++)
#pragma unroll
    for (int j = 0; j < 4; j++) acc[i][j] = 0.f;

  auto stage = [&](int s) {
    char* base = lds + (s & 3) * 32768;
    int k0 = s * 32;
#pragma unroll
    for (int i = 0; i < 2; i++) {
      int L = i * 8192 + tid * 16;
      int row = L >> 6, g = (L >> 4) & 3;
      int gs = g ^ ((row >> 1) & 3);
      GLD16((const char*)(Ab + (size_t)row * D_DIM + k0) + gs * 16,
            base + i * 8192 + wid * 1024);
      GLD16((const char*)(Bb + (size_t)row * D_DIM + k0) + gs * 16,
            base + 16384 + i * 8192 + wid * 1024);
    }
  };

  asm volatile("s_waitcnt vmcnt(0)" ::: "memory");
  stage(0);
  stage(1);
#pragma unroll 1
  for (int g = 0; g < 30; g++) G_PHASE(g, "8", true, 4, 32768, 16384);
  G_PHASE(30, "4", false, 4, 32768, 16384);
  G_PHASE(31, "0", false, 4, 32768, 16384);

  int rq = lane >> 4;
#pragma unroll
  for (int fm = 0; fm < 8; fm++)
#pragma unroll
    for (int fnp = 0; fnp < 2; fnp++)
#pragma unroll
      for (int j = 0; j < 4; j++) {
        float v1 = acc[fm][2 * fnp][j], v3 = acc[fm][2 * fnp + 1][j];
        float h = (v1 / (1.f + expf(-v1))) * v3;  // silu(v1)*v3
        int r = row0 + wr * 128 + fm * 16 + rq * 4 + j;
        int c = (n0 >> 1) + wc * 32 + fnp * 16 + rsel;
        Hb[(size_t)r * H_DIM + c] = __float2bfloat16(h);
      }
}

// ---------------- GEMM2: Y = Hb @ w2t^T (fp32 out), 256x128 tile ----------------
__global__ __launch_bounds__(512, 2) void gemm2_kernel(const __hip_bfloat16* __restrict__ Hb,
                                                       const __hip_bfloat16* __restrict__ w2t,
                                                       float* __restrict__ Y,
                                                       const int* __restrict__ meta) {
  int m, nIdx;
  tile_from_bid(blockIdx.x, (D_DIM / 128) * MT2_MAX, MT2_MAX, &m, &nIdx);
  if (m >= meta[MI_TOTAL]) return;
  int e = meta[MI_MTE + m];
  int row0 = meta[MI_MTB + m];
  int n0 = nIdx * 128;
  __shared__ __align__(16) char lds[98304];  // 4 slices x (A 16KB + B 8KB)
  const int tid = threadIdx.x, wid = tid >> 6, lane = tid & 63;
  const int wr = wid >> 2, wc = wid & 3, rsel = lane & 15, kg = lane >> 4;
  const __hip_bfloat16* Ab = Hb + (size_t)row0 * H_DIM;
  const __hip_bfloat16* Bb = w2t + ((size_t)e * D_DIM + n0) * H_DIM;

  f32x4 acc[8][2];
#pragma unroll
  for (int i = 0; i < 8; i++)
#pragma unroll
    for (int j = 0; j < 2; j++) acc[i][j] = 0.f;

  auto stage = [&](int s) {
    char* base = lds + (s & 3) * 24576;
    int k0 = s * 32;
#pragma unroll
    for (int i = 0; i < 2; i++) {
      int L = i * 8192 + tid * 16;
      int row = L >> 6, g = (L >> 4) & 3;
      int gs = g ^ ((row >> 1) & 3);
      GLD16((const char*)(Ab + (size_t)row * H_DIM + k0) + gs * 16,
            base + i * 8192 + wid * 1024);
    }
    {
      int L = tid * 16;
      int row = L >> 6, g = (L >> 4) & 3;
      int gs = g ^ ((row >> 1) & 3);
      GLD16((const char*)(Bb + (size_t)row * H_DIM + k0) + gs * 16,
            base + 16384 + wid * 1024);
    }
  };

  asm volatile("s_waitcnt vmcnt(0)" ::: "memory");
  stage(0);
  stage(1);
#pragma unroll 1
  for (int g = 0; g < 86; g++) G_PHASE(g, "6", true, 2, 24576, 16384);
  G_PHASE(86, "3", false, 2, 24576, 16384);
  G_PHASE(87, "0", false, 2, 24576, 16384);

  int rq = lane >> 4;
#pragma unroll
  for (int fm = 0; fm < 8; fm++)
#pragma unroll
    for (int fn = 0; fn < 2; fn++)
#pragma unroll
      for (int j = 0; j < 4; j++) {
        int r = row0 + wr * 128 + fm * 16 + rq * 4 + j;
        int c = n0 + wc * 32 + fn * 16 + rsel;
        Y[(size_t)r * D_DIM + c] = acc[fm][fn][j];
      }
}

// ---------------- combine: out[t] = w0*Y[p0] + w1*Y[p1] ----------------
__global__ __launch_bounds__(256) void combine_kernel(const int* __restrict__ slot_pos,
                                                      const float* __restrict__ slot_w,
                                                      const float* __restrict__ Y,
                                                      float* __restrict__ outp) {
  int tok = blockIdx.x;
  int p0 = slot_pos[tok * 2], p1 = slot_pos[tok * 2 + 1];
  float w0 = slot_w[tok * 2], w1 = slot_w[tok * 2 + 1];
  float4 y0 = ((const float4*)(Y + (size_t)p0 * D_DIM))[threadIdx.x];
  float4 y1 = ((const float4*)(Y + (size_t)p1 * D_DIM))[threadIdx.x];
  float4 r;
  r.x = w0 * y0.x + w1 * y1.x;
  r.y = w0 * y0.y + w1 * y1.y;
  r.z = w0 * y0.z + w1 * y1.z;
  r.w = w0 * y0.w + w1 * y1.w;
  ((float4*)(outp + (size_t)tok * D_DIM))[threadIdx.x] = r;
}

// ---------------- launch ----------------
extern "C" void kernel_launch(void* const* d_in, const int* in_sizes, int n_in,
                              void* d_out, int out_size, void* d_ws, size_t ws_size,
                              hipStream_t stream) {
  const float* x = (const float*)d_in[0];
  const float* Wr = (const float*)d_in[1];
  const float* w1 = (const float*)d_in[2];
  const float* w3 = (const float*)d_in[3];
  const float* w2 = (const float*)d_in[4];
  float* outp = (float*)d_out;

  char* ws = (char*)d_ws;
  size_t off = 0;
  auto alloc = [&](size_t bytes) -> char* {
    char* p = ws + off;
    off += (bytes + 255) & ~(size_t)255;
    return p;
  };
  __hip_bfloat16* w13t = (__hip_bfloat16*)alloc((size_t)E_EXP * 2 * H_DIM * D_DIM * 2);
  __hip_bfloat16* w2t = (__hip_bfloat16*)alloc((size_t)E_EXP * D_DIM * H_DIM * 2);
  __hip_bfloat16* Xg = (__hip_bfloat16*)alloc((size_t)CAP_ROWS * D_DIM * 2);
  __hip_bfloat16* Hb = (__hip_bfloat16*)alloc((size_t)CAP_ROWS * H_DIM * 2);
  float* Y = (float*)alloc((size_t)CAP_ROWS * D_DIM * 4);
  float* slot_w = (float*)alloc(NSLOT * 4);
  int* slot_pos = (int*)alloc(NSLOT * 4);
  int* expert_sel = (int*)alloc(NSLOT * 4);
  float* Pbuf = (float*)alloc(2048 * 8 * 4);
  int* meta = (int*)alloc(2048);
  (void)ws_size; (void)in_sizes; (void)n_in; (void)out_size;

  init_kernel<<<dim3(1), dim3(64), 0, stream>>>(meta);
  w13_transpose<<<dim3(H_DIM / 64, D_DIM / 64, 2 * E_EXP), dim3(256), 0, stream>>>(w1, w3, w13t);
  transpose_convert<H_DIM, D_DIM><<<dim3(D_DIM / 64, H_DIM / 64, E_EXP), dim3(256), 0, stream>>>(w2, w2t);
  router_kernel<<<dim3(T_TOK / 4), dim3(256), 0, stream>>>(x, Wr, meta, Pbuf, expert_sel, slot_w);
  offsets_kernel<<<dim3(1), dim3(256), 0, stream>>>(meta, Pbuf, outp + (size_t)T_TOK * D_DIM);
  assign_kernel<<<dim3(NSLOT / 256), dim3(256), 0, stream>>>(expert_sel, meta, slot_pos);
  gather_kernel<<<dim3(NSLOT / 4), dim3(256), 0, stream>>>(slot_pos, x, Xg);
  gemm1_kernel<<<dim3((2 * H_DIM / 256) * MT2_MAX), dim3(512), 0, stream>>>(Xg, w13t, Hb, meta);
  gemm2_kernel<<<dim3((D_DIM / 128) * MT2_MAX), dim3(512), 0, stream>>>(Hb, w2t, Y, meta);
  combine_kernel<<<dim3(T_TOK), dim3(256), 0, stream>>>(slot_pos, slot_w, Y, outp);
}

// Round 5
// 723.482 us; speedup vs baseline: 1.0441x; 1.0441x over previous
//
#include <hip/hip_runtime.h>
#include <hip/hip_bf16.h>
#include <stdint.h>

// MoE top-2 (T=8192, D=1024, H=2816, E=8) — sparse grouped-GEMM implementation.
// R4 (resubmit after infra failure): proven 2-barrier BK=64 GEMM structure;
// gemm1 single-B via W13 interleave (fused SiLU); gemm2 BN=256 + bf16 Y;
// token-wise gather.

#define T_TOK 8192
#define D_DIM 1024
#define H_DIM 2816
#define E_EXP 8
#define NSLOT 16384       // T * 2
#define CAP_ROWS 17408    // 136 * 128
#define MT_MAX 136

// meta int layout
#define MI_TOTAL 0
#define MI_CNT 8
#define MI_POS 16
#define MI_MTE 32
#define MI_MTB (32 + MT_MAX)

typedef __attribute__((ext_vector_type(8))) short short8;
typedef __attribute__((ext_vector_type(4))) float f32x4;

#define GLD16(gsrc, ldst) __builtin_amdgcn_global_load_lds( \
    (const __attribute__((address_space(1))) void*)(gsrc),  \
    (__attribute__((address_space(3))) void*)(ldst), 16, 0, 0)

// ---------------- init ----------------
__global__ __launch_bounds__(64) void init_kernel(int* meta) {
  if (threadIdx.x < E_EXP) meta[MI_CNT + threadIdx.x] = 0;
}

// ---------------- w2 transpose + f32->bf16 ----------------
// in: (E, R, C) f32   out: (E, C, R) bf16.  64x64 tiles.
template <int R, int C>
__global__ __launch_bounds__(256) void transpose_convert(const float* __restrict__ in,
                                                         __hip_bfloat16* __restrict__ outp) {
  int e = blockIdx.z;
  int c0 = blockIdx.x * 64, r0 = blockIdx.y * 64;
  __shared__ float tile[64][65];
  int tid = threadIdx.x;
  int lc = (tid & 15) * 4;
  int lr = tid >> 4;
  const float* src = in + ((size_t)e * R + r0) * C + c0;
#pragma unroll
  for (int i = 0; i < 4; i++) {
    float4 v = *(const float4*)(src + (size_t)(lr + i * 16) * C + lc);
    tile[lr + i * 16][lc + 0] = v.x;
    tile[lr + i * 16][lc + 1] = v.y;
    tile[lr + i * 16][lc + 2] = v.z;
    tile[lr + i * 16][lc + 3] = v.w;
  }
  __syncthreads();
  __hip_bfloat16* dst = outp + ((size_t)e * C + c0) * R + r0;
  int rB = (tid & 7) * 8;
#pragma unroll
  for (int i = 0; i < 2; i++) {
    int c = (tid >> 3) + i * 32;
    __align__(16) __hip_bfloat16 o[8];
#pragma unroll
    for (int k = 0; k < 8; k++) o[k] = __float2bfloat16(tile[rB + k][c]);
    *(short8*)(dst + (size_t)c * R + rB) = *(const short8*)o;
  }
}

// ---------------- W13 interleaved transpose ----------------
// w1,w3: (E, D, H) f32 -> w13t: (E, 2H, D) bf16, row(h,which) = 2*(h&~15)+(h&15)+16*which
__global__ __launch_bounds__(256) void w13_transpose(const float* __restrict__ w1,
                                                     const float* __restrict__ w3,
                                                     __hip_bfloat16* __restrict__ w13t) {
  int z = blockIdx.z;  // 0..2E-1
  int e = z >> 1, w3f = z & 1;
  const float* in = w3f ? w3 : w1;
  int h0 = blockIdx.x * 64, d0 = blockIdx.y * 64;
  __shared__ float tile[64][65];
  int tid = threadIdx.x;
  int lc = (tid & 15) * 4;
  int lr = tid >> 4;
  const float* src = in + ((size_t)e * D_DIM + d0) * H_DIM + h0;
#pragma unroll
  for (int i = 0; i < 4; i++) {
    float4 v = *(const float4*)(src + (size_t)(lr + i * 16) * H_DIM + lc);
    tile[lr + i * 16][lc + 0] = v.x;
    tile[lr + i * 16][lc + 1] = v.y;
    tile[lr + i * 16][lc + 2] = v.z;
    tile[lr + i * 16][lc + 3] = v.w;
  }
  __syncthreads();
  __hip_bfloat16* dstE = w13t + (size_t)e * (2 * H_DIM) * D_DIM;
  int rB = (tid & 7) * 8;  // d offset within tile
#pragma unroll
  for (int i = 0; i < 2; i++) {
    int hh = (tid >> 3) + i * 32;
    int habs = h0 + hh;
    int rw = 2 * (habs & ~15) + (habs & 15) + (w3f ? 16 : 0);
    __align__(16) __hip_bfloat16 o[8];
#pragma unroll
    for (int k = 0; k < 8; k++) o[k] = __float2bfloat16(tile[rB + k][hh]);
    *(short8*)(dstE + (size_t)rw * D_DIM + d0 + rB) = *(const short8*)o;
  }
}

// ---------------- router ----------------
__global__ __launch_bounds__(256) void router_kernel(const float* __restrict__ x,
                                                     const float* __restrict__ Wr,
                                                     int* __restrict__ meta,
                                                     float* __restrict__ Pbuf,
                                                     int* __restrict__ expert_sel,
                                                     float* __restrict__ slot_w) {
  int wave = threadIdx.x >> 6, lane = threadIdx.x & 63;
  int tok = blockIdx.x * 4 + wave;
  const float* xr = x + (size_t)tok * D_DIM;
  float acc[8];
#pragma unroll
  for (int e = 0; e < 8; e++) acc[e] = 0.f;
  for (int d = lane; d < D_DIM; d += 64) {
    float xv = xr[d];
    const float4* w4 = (const float4*)(Wr + d * 8);
    float4 wa = w4[0], wb = w4[1];
    acc[0] += xv * wa.x; acc[1] += xv * wa.y; acc[2] += xv * wa.z; acc[3] += xv * wa.w;
    acc[4] += xv * wb.x; acc[5] += xv * wb.y; acc[6] += xv * wb.z; acc[7] += xv * wb.w;
  }
#pragma unroll
  for (int e = 0; e < 8; e++) {
#pragma unroll
    for (int off = 32; off >= 1; off >>= 1) acc[e] += __shfl_xor(acc[e], off);
  }
  float mx = acc[0];
#pragma unroll
  for (int e = 1; e < 8; e++) mx = fmaxf(mx, acc[e]);
  float p[8], s = 0.f;
#pragma unroll
  for (int e = 0; e < 8; e++) { p[e] = expf(acc[e] - mx); s += p[e]; }
  float inv = 1.f / s;
#pragma unroll
  for (int e = 0; e < 8; e++) p[e] *= inv;
  int i0 = 0;
#pragma unroll
  for (int e = 1; e < 8; e++) if (p[e] > p[i0]) i0 = e;
  int i1 = (i0 == 0) ? 1 : 0;
#pragma unroll
  for (int e = 0; e < 8; e++) if (e != i0 && p[e] > p[i1]) i1 = e;
  float wsum = p[i0] + p[i1];

  __shared__ float sP[4][8];
  if (lane == 0) {
    expert_sel[tok * 2] = i0;
    expert_sel[tok * 2 + 1] = i1;
    slot_w[tok * 2] = p[i0] / wsum;
    slot_w[tok * 2 + 1] = p[i1] / wsum;
    atomicAdd(&meta[MI_CNT + i0], 1);
    atomicAdd(&meta[MI_CNT + i1], 1);
#pragma unroll
    for (int e = 0; e < 8; e++) sP[wave][e] = p[e];
  }
  __syncthreads();
  if (threadIdx.x < 8)
    Pbuf[threadIdx.x * 2048 + blockIdx.x] =
        sP[0][threadIdx.x] + sP[1][threadIdx.x] + sP[2][threadIdx.x] + sP[3][threadIdx.x];
}

// ---------------- offsets + aux loss ----------------
__global__ __launch_bounds__(256) void offsets_kernel(int* __restrict__ meta,
                                                      const float* __restrict__ Pbuf,
                                                      float* __restrict__ aux_out) {
  __shared__ float red[8][33];
  int t = threadIdx.x;
  int e = t >> 5, j = t & 31;
  float s = 0.f;
  for (int c = j; c < 2048; c += 32) s += Pbuf[e * 2048 + c];
  red[e][j] = s;
  __syncthreads();
  if (t == 0) {
    float psum[8];
    for (int ee = 0; ee < 8; ee++) {
      float ss = 0.f;
      for (int k = 0; k < 32; k++) ss += red[ee][k];
      psum[ee] = ss;
    }
    int off = 0, nt = 0;
    float aux = 0.f;
    for (int ee = 0; ee < 8; ee++) {
      int c = meta[MI_CNT + ee];
      meta[MI_POS + ee] = off;
      int tiles = (c + 127) >> 7;
      for (int jj = 0; jj < tiles; jj++) { meta[MI_MTE + nt] = ee; meta[MI_MTB + nt] = off + jj * 128; nt++; }
      off += tiles * 128;
      aux += ((float)c / 16384.f) * (psum[ee] / 8192.f);
    }
    meta[MI_TOTAL] = nt;
    *aux_out = 8.f * aux;
  }
}

// ---------------- assign: ballot-aggregated positions ----------------
__global__ __launch_bounds__(256) void assign_kernel(const int* __restrict__ expert_sel,
                                                     int* __restrict__ meta,
                                                     int* __restrict__ slot_pos) {
  int tid = threadIdx.x, wave = tid >> 6, lane = tid & 63;
  int slot = blockIdx.x * 256 + tid;
  int e = expert_sel[slot];
  __shared__ int cnt[4][8];
  __shared__ int base[8];
  __shared__ int woff[4][8];
  int rank = 0;
#pragma unroll
  for (int ee = 0; ee < 8; ee++) {
    unsigned long long msk = __ballot(e == ee);
    if (lane == 0) cnt[wave][ee] = __popcll(msk);
    if (e == ee) rank = __popcll(msk & ((1ull << lane) - 1ull));
  }
  __syncthreads();
  if (tid < 8) {
    int c0 = cnt[0][tid], c1 = cnt[1][tid], c2 = cnt[2][tid], c3 = cnt[3][tid];
    int tot = c0 + c1 + c2 + c3;
    base[tid] = atomicAdd(&meta[MI_POS + tid], tot);
    woff[0][tid] = 0; woff[1][tid] = c0; woff[2][tid] = c0 + c1; woff[3][tid] = c0 + c1 + c2;
  }
  __syncthreads();
  slot_pos[slot] = base[e] + woff[wave][e] + rank;
}

// ---------------- gather: one read per token, write both slots ----------------
__global__ __launch_bounds__(256) void gather_kernel(const int* __restrict__ slot_pos,
                                                     const float* __restrict__ x,
                                                     __hip_bfloat16* __restrict__ Xg) {
  int wave = threadIdx.x >> 6, lane = threadIdx.x & 63;
  int tok = blockIdx.x * 4 + wave;
  int p0 = slot_pos[tok * 2], p1 = slot_pos[tok * 2 + 1];
  const float4* src = (const float4*)(x + (size_t)tok * D_DIM);
  __hip_bfloat16* d0 = Xg + (size_t)p0 * D_DIM;
  __hip_bfloat16* d1 = Xg + (size_t)p1 * D_DIM;
#pragma unroll
  for (int p = 0; p < 4; p++) {
    float4 v = src[p * 64 + lane];
    union { ushort4 u4; __hip_bfloat16 h[4]; } cv;
    cv.h[0] = __float2bfloat16(v.x);
    cv.h[1] = __float2bfloat16(v.y);
    cv.h[2] = __float2bfloat16(v.z);
    cv.h[3] = __float2bfloat16(v.w);
    *(ushort4*)(d0 + (p * 64 + lane) * 4) = cv.u4;
    *(ushort4*)(d1 + (p * 64 + lane) * 4) = cv.u4;
  }
}

// ---------------- GEMM helpers (BK=64) ----------------
// LDS tile rows of 128B; 16B granule g (0..7) XOR-swizzled with row&7.
__device__ __forceinline__ short8 frag_read64(const char* tile, int row, int gk) {
  int byte = (row << 7) | ((gk ^ (row & 7)) << 4);
  return *(const short8*)(tile + byte);
}

// stage NITER*4096 bytes (256 threads x 16B) of [rows][64] bf16 tile
template <int NITER>
__device__ __forceinline__ void stage_rows(const __hip_bfloat16* gbase, int ld, char* tile,
                                           int tid) {
#pragma unroll
  for (int i = 0; i < NITER; i++) {
    int L = i * 4096 + tid * 16;
    int row = L >> 7;
    int g = (L >> 4) & 7;
    int gs = g ^ (row & 7);  // pre-swizzled global source, linear LDS dest
    const char* src = (const char*)(gbase + (size_t)row * ld) + gs * 16;
    GLD16(src, tile + i * 4096 + (tid >> 6) * 1024);
  }
}

// bijective XCD-chunked swizzle; m fastest within chunk (nwg % 8 == 0)
__device__ __forceinline__ void tile_from_bid(int bid, int nwg, int mmax, int* m, int* n) {
  int cpx = nwg >> 3;
  int u = (bid & 7) * cpx + (bid >> 3);
  *n = u / mmax;
  *m = u % mmax;
}

// ---------------- GEMM1: Hb = silu/fuse( Xg @ w13t^T ), 128x(256 interleaved) ----------------
__global__ __launch_bounds__(256, 2) void gemm1_kernel(const __hip_bfloat16* __restrict__ Xg,
                                                       const __hip_bfloat16* __restrict__ w13t,
                                                       __hip_bfloat16* __restrict__ Hb,
                                                       const int* __restrict__ meta) {
  int m, nIdx;
  tile_from_bid(blockIdx.x, (2 * H_DIM / 256) * MT_MAX, MT_MAX, &m, &nIdx);
  if (m >= meta[MI_TOTAL]) return;
  int e = meta[MI_MTE + m];
  int row0 = meta[MI_MTB + m];
  int n0 = nIdx * 256;
  __shared__ __align__(16) char ldsA[16384];
  __shared__ __align__(16) char ldsB[32768];
  int tid = threadIdx.x, wave = tid >> 6, lane = tid & 63;
  int wr = wave >> 1, wc = wave & 1;
  const __hip_bfloat16* Ab = Xg + (size_t)row0 * D_DIM;
  const __hip_bfloat16* Bb = w13t + ((size_t)e * (2 * H_DIM) + n0) * D_DIM;

  f32x4 acc[4][8];
#pragma unroll
  for (int i = 0; i < 4; i++)
#pragma unroll
    for (int j = 0; j < 8; j++) acc[i][j] = 0.f;

  int rsel = lane & 15, kg = lane >> 4;
  for (int k0 = 0; k0 < D_DIM; k0 += 64) {
    stage_rows<4>(Ab + k0, D_DIM, ldsA, tid);
    stage_rows<8>(Bb + k0, D_DIM, ldsB, tid);
    asm volatile("s_waitcnt vmcnt(0)" ::: "memory");
    __syncthreads();
#pragma unroll
    for (int kk = 0; kk < 2; kk++) {
      int gk = kk * 4 + kg;
      short8 a[4], b[8];
#pragma unroll
      for (int f = 0; f < 4; f++) a[f] = frag_read64(ldsA, wr * 64 + f * 16 + rsel, gk);
#pragma unroll
      for (int f = 0; f < 8; f++) b[f] = frag_read64(ldsB, wc * 128 + f * 16 + rsel, gk);
#pragma unroll
      for (int fm = 0; fm < 4; fm++)
#pragma unroll
        for (int fn = 0; fn < 8; fn++)
          acc[fm][fn] = __builtin_amdgcn_mfma_f32_16x16x32_bf16(a[fm], b[fn], acc[fm][fn], 0, 0, 0);
    }
    __syncthreads();
  }
  int rq = lane >> 4;
#pragma unroll
  for (int fm = 0; fm < 4; fm++)
#pragma unroll
    for (int fnp = 0; fnp < 4; fnp++)
#pragma unroll
      for (int j = 0; j < 4; j++) {
        float v1 = acc[fm][2 * fnp][j], v3 = acc[fm][2 * fnp + 1][j];
        float h = (v1 / (1.f + expf(-v1))) * v3;  // silu(v1)*v3
        int r = row0 + wr * 64 + fm * 16 + rq * 4 + j;
        int c = (n0 >> 1) + wc * 64 + fnp * 16 + rsel;
        Hb[(size_t)r * H_DIM + c] = __float2bfloat16(h);
      }
}

// ---------------- GEMM2: Y = Hb @ w2t^T (bf16 out), 128x256 tile ----------------
__global__ __launch_bounds__(256, 2) void gemm2_kernel(const __hip_bfloat16* __restrict__ Hb,
                                                       const __hip_bfloat16* __restrict__ w2t,
                                                       __hip_bfloat16* __restrict__ Y,
                                                       const int* __restrict__ meta) {
  int m, nIdx;
  tile_from_bid(blockIdx.x, (D_DIM / 256) * MT_MAX, MT_MAX, &m, &nIdx);
  if (m >= meta[MI_TOTAL]) return;
  int e = meta[MI_MTE + m];
  int row0 = meta[MI_MTB + m];
  int n0 = nIdx * 256;
  __shared__ __align__(16) char ldsA[16384];
  __shared__ __align__(16) char ldsB[32768];
  int tid = threadIdx.x, wave = tid >> 6, lane = tid & 63;
  int wr = wave >> 1, wc = wave & 1;
  const __hip_bfloat16* Ab = Hb + (size_t)row0 * H_DIM;
  const __hip_bfloat16* Bb = w2t + ((size_t)e * D_DIM + n0) * H_DIM;

  f32x4 acc[4][8];
#pragma unroll
  for (int i = 0; i < 4; i++)
#pragma unroll
    for (int j = 0; j < 8; j++) acc[i][j] = 0.f;

  int rsel = lane & 15, kg = lane >> 4;
  for (int k0 = 0; k0 < H_DIM; k0 += 64) {
    stage_rows<4>(Ab + k0, H_DIM, ldsA, tid);
    stage_rows<8>(Bb + k0, H_DIM, ldsB, tid);
    asm volatile("s_waitcnt vmcnt(0)" ::: "memory");
    __syncthreads();
#pragma unroll
    for (int kk = 0; kk < 2; kk++) {
      int gk = kk * 4 + kg;
      short8 a[4], b[8];
#pragma unroll
      for (int f = 0; f < 4; f++) a[f] = frag_read64(ldsA, wr * 64 + f * 16 + rsel, gk);
#pragma unroll
      for (int f = 0; f < 8; f++) b[f] = frag_read64(ldsB, wc * 128 + f * 16 + rsel, gk);
#pragma unroll
      for (int fm = 0; fm < 4; fm++)
#pragma unroll
        for (int fn = 0; fn < 8; fn++)
          acc[fm][fn] = __builtin_amdgcn_mfma_f32_16x16x32_bf16(a[fm], b[fn], acc[fm][fn], 0, 0, 0);
    }
    __syncthreads();
  }
  int rq = lane >> 4;
#pragma unroll
  for (int fm = 0; fm < 4; fm++)
#pragma unroll
    for (int fn = 0; fn < 8; fn++)
#pragma unroll
      for (int j = 0; j < 4; j++) {
        int r = row0 + wr * 64 + fm * 16 + rq * 4 + j;
        int c = n0 + wc * 128 + fn * 16 + rsel;
        Y[(size_t)r * D_DIM + c] = __float2bfloat16(acc[fm][fn][j]);
      }
}

// ---------------- combine: out[t] = w0*Y[p0] + w1*Y[p1] (bf16 Y) ----------------
__global__ __launch_bounds__(256) void combine_kernel(const int* __restrict__ slot_pos,
                                                      const float* __restrict__ slot_w,
                                                      const __hip_bfloat16* __restrict__ Y,
                                                      float* __restrict__ outp) {
  int tok = blockIdx.x;
  int p0 = slot_pos[tok * 2], p1 = slot_pos[tok * 2 + 1];
  float w0 = slot_w[tok * 2], w1 = slot_w[tok * 2 + 1];
  int i4 = threadIdx.x;  // 256 threads x 4 elems
  ushort4 a = *(const ushort4*)(Y + (size_t)p0 * D_DIM + i4 * 4);
  ushort4 b = *(const ushort4*)(Y + (size_t)p1 * D_DIM + i4 * 4);
  union { ushort u; __hip_bfloat16 h; } c0, c1;
  float4 r;
  c0.u = a.x; c1.u = b.x; r.x = w0 * __bfloat162float(c0.h) + w1 * __bfloat162float(c1.h);
  c0.u = a.y; c1.u = b.y; r.y = w0 * __bfloat162float(c0.h) + w1 * __bfloat162float(c1.h);
  c0.u = a.z; c1.u = b.z; r.z = w0 * __bfloat162float(c0.h) + w1 * __bfloat162float(c1.h);
  c0.u = a.w; c1.u = b.w; r.w = w0 * __bfloat162float(c0.h) + w1 * __bfloat162float(c1.h);
  ((float4*)(outp + (size_t)tok * D_DIM))[i4] = r;
}

// ---------------- launch ----------------
extern "C" void kernel_launch(void* const* d_in, const int* in_sizes, int n_in,
                              void* d_out, int out_size, void* d_ws, size_t ws_size,
                              hipStream_t stream) {
  const float* x = (const float*)d_in[0];
  const float* Wr = (const float*)d_in[1];
  const float* w1 = (const float*)d_in[2];
  const float* w3 = (const float*)d_in[3];
  const float* w2 = (const float*)d_in[4];
  float* outp = (float*)d_out;

  char* ws = (char*)d_ws;
  size_t off = 0;
  auto alloc = [&](size_t bytes) -> char* {
    char* p = ws + off;
    off += (bytes + 255) & ~(size_t)255;
    return p;
  };
  __hip_bfloat16* w13t = (__hip_bfloat16*)alloc((size_t)E_EXP * 2 * H_DIM * D_DIM * 2);
  __hip_bfloat16* w2t = (__hip_bfloat16*)alloc((size_t)E_EXP * D_DIM * H_DIM * 2);
  __hip_bfloat16* Xg = (__hip_bfloat16*)alloc((size_t)CAP_ROWS * D_DIM * 2);
  __hip_bfloat16* Hb = (__hip_bfloat16*)alloc((size_t)CAP_ROWS * H_DIM * 2);
  __hip_bfloat16* Y = (__hip_bfloat16*)alloc((size_t)CAP_ROWS * D_DIM * 2);
  float* slot_w = (float*)alloc(NSLOT * 4);
  int* slot_pos = (int*)alloc(NSLOT * 4);
  int* expert_sel = (int*)alloc(NSLOT * 4);
  float* Pbuf = (float*)alloc(2048 * 8 * 4);
  int* meta = (int*)alloc(2048);
  (void)ws_size; (void)in_sizes; (void)n_in; (void)out_size;

  init_kernel<<<dim3(1), dim3(64), 0, stream>>>(meta);
  w13_transpose<<<dim3(H_DIM / 64, D_DIM / 64, 2 * E_EXP), dim3(256), 0, stream>>>(w1, w3, w13t);
  transpose_convert<H_DIM, D_DIM><<<dim3(D_DIM / 64, H_DIM / 64, E_EXP), dim3(256), 0, stream>>>(w2, w2t);
  router_kernel<<<dim3(T_TOK / 4), dim3(256), 0, stream>>>(x, Wr, meta, Pbuf, expert_sel, slot_w);
  offsets_kernel<<<dim3(1), dim3(256), 0, stream>>>(meta, Pbuf, outp + (size_t)T_TOK * D_DIM);
  assign_kernel<<<dim3(NSLOT / 256), dim3(256), 0, stream>>>(expert_sel, meta, slot_pos);
  gather_kernel<<<dim3(T_TOK / 4), dim3(256), 0, stream>>>(slot_pos, x, Xg);
  gemm1_kernel<<<dim3((2 * H_DIM / 256) * MT_MAX), dim3(256), 0, stream>>>(Xg, w13t, Hb, meta);
  gemm2_kernel<<<dim3((D_DIM / 256) * MT_MAX), dim3(256), 0, stream>>>(Hb, w2t, Y, meta);
  combine_kernel<<<dim3(T_TOK), dim3(256), 0, stream>>>(slot_pos, slot_w, Y, outp);
}

// Round 6
// 611.861 us; speedup vs baseline: 1.2346x; 1.1824x over previous
//
#include <hip/hip_runtime.h>
#include <hip/hip_bf16.h>
#include <stdint.h>

// MoE top-2 (T=8192, D=1024, H=2816, E=8) — sparse grouped-GEMM implementation.
// R6: gemm1 -> 256x256 tile (512thr/8wave, 2-phase); histogram-based offsets
// (no init kernel, no router atomics); dual tile lists (256-step gemm1,
// 128-step gemm2); gemm2/transposes/gather/combine unchanged from R5.

#define T_TOK 8192
#define D_DIM 1024
#define H_DIM 2816
#define E_EXP 8
#define NSLOT 16384       // T * 2
#define CAP_ROWS 18432    // 72 * 256
#define MT1_MAX 72        // 256-row tiles
#define MT2_MAX 136       // 128-row tiles

// meta int layout
#define MI_T1 0
#define MI_T2 1
#define MI_POS 8
#define MI_MTE1 16
#define MI_MTB1 (16 + MT1_MAX)
#define MI_MTE2 (16 + 2 * MT1_MAX)
#define MI_MTB2 (16 + 2 * MT1_MAX + MT2_MAX)

typedef __attribute__((ext_vector_type(8))) short short8;
typedef __attribute__((ext_vector_type(4))) float f32x4;

#define GLD16(gsrc, ldst) __builtin_amdgcn_global_load_lds( \
    (const __attribute__((address_space(1))) void*)(gsrc),  \
    (__attribute__((address_space(3))) void*)(ldst), 16, 0, 0)

// ---------------- w2 transpose + f32->bf16 ----------------
// in: (E, R, C) f32   out: (E, C, R) bf16.  64x64 tiles.
template <int R, int C>
__global__ __launch_bounds__(256) void transpose_convert(const float* __restrict__ in,
                                                         __hip_bfloat16* __restrict__ outp) {
  int e = blockIdx.z;
  int c0 = blockIdx.x * 64, r0 = blockIdx.y * 64;
  __shared__ float tile[64][65];
  int tid = threadIdx.x;
  int lc = (tid & 15) * 4;
  int lr = tid >> 4;
  const float* src = in + ((size_t)e * R + r0) * C + c0;
#pragma unroll
  for (int i = 0; i < 4; i++) {
    float4 v = *(const float4*)(src + (size_t)(lr + i * 16) * C + lc);
    tile[lr + i * 16][lc + 0] = v.x;
    tile[lr + i * 16][lc + 1] = v.y;
    tile[lr + i * 16][lc + 2] = v.z;
    tile[lr + i * 16][lc + 3] = v.w;
  }
  __syncthreads();
  __hip_bfloat16* dst = outp + ((size_t)e * C + c0) * R + r0;
  int rB = (tid & 7) * 8;
#pragma unroll
  for (int i = 0; i < 2; i++) {
    int c = (tid >> 3) + i * 32;
    __align__(16) __hip_bfloat16 o[8];
#pragma unroll
    for (int k = 0; k < 8; k++) o[k] = __float2bfloat16(tile[rB + k][c]);
    *(short8*)(dst + (size_t)c * R + rB) = *(const short8*)o;
  }
}

// ---------------- W13 interleaved transpose ----------------
// w1,w3: (E, D, H) f32 -> w13t: (E, 2H, D) bf16, row(h,which) = 2*(h&~15)+(h&15)+16*which
__global__ __launch_bounds__(256) void w13_transpose(const float* __restrict__ w1,
                                                     const float* __restrict__ w3,
                                                     __hip_bfloat16* __restrict__ w13t) {
  int z = blockIdx.z;  // 0..2E-1
  int e = z >> 1, w3f = z & 1;
  const float* in = w3f ? w3 : w1;
  int h0 = blockIdx.x * 64, d0 = blockIdx.y * 64;
  __shared__ float tile[64][65];
  int tid = threadIdx.x;
  int lc = (tid & 15) * 4;
  int lr = tid >> 4;
  const float* src = in + ((size_t)e * D_DIM + d0) * H_DIM + h0;
#pragma unroll
  for (int i = 0; i < 4; i++) {
    float4 v = *(const float4*)(src + (size_t)(lr + i * 16) * H_DIM + lc);
    tile[lr + i * 16][lc + 0] = v.x;
    tile[lr + i * 16][lc + 1] = v.y;
    tile[lr + i * 16][lc + 2] = v.z;
    tile[lr + i * 16][lc + 3] = v.w;
  }
  __syncthreads();
  __hip_bfloat16* dstE = w13t + (size_t)e * (2 * H_DIM) * D_DIM;
  int rB = (tid & 7) * 8;  // d offset within tile
#pragma unroll
  for (int i = 0; i < 2; i++) {
    int hh = (tid >> 3) + i * 32;
    int habs = h0 + hh;
    int rw = 2 * (habs & ~15) + (habs & 15) + (w3f ? 16 : 0);
    __align__(16) __hip_bfloat16 o[8];
#pragma unroll
    for (int k = 0; k < 8; k++) o[k] = __float2bfloat16(tile[rB + k][hh]);
    *(short8*)(dstE + (size_t)rw * D_DIM + d0 + rB) = *(const short8*)o;
  }
}

// ---------------- router (no atomics) ----------------
__global__ __launch_bounds__(256) void router_kernel(const float* __restrict__ x,
                                                     const float* __restrict__ Wr,
                                                     float* __restrict__ Pbuf,
                                                     int* __restrict__ expert_sel,
                                                     float* __restrict__ slot_w) {
  int wave = threadIdx.x >> 6, lane = threadIdx.x & 63;
  int tok = blockIdx.x * 4 + wave;
  const float* xr = x + (size_t)tok * D_DIM;
  float acc[8];
#pragma unroll
  for (int e = 0; e < 8; e++) acc[e] = 0.f;
  for (int d = lane; d < D_DIM; d += 64) {
    float xv = xr[d];
    const float4* w4 = (const float4*)(Wr + d * 8);
    float4 wa = w4[0], wb = w4[1];
    acc[0] += xv * wa.x; acc[1] += xv * wa.y; acc[2] += xv * wa.z; acc[3] += xv * wa.w;
    acc[4] += xv * wb.x; acc[5] += xv * wb.y; acc[6] += xv * wb.z; acc[7] += xv * wb.w;
  }
#pragma unroll
  for (int e = 0; e < 8; e++) {
#pragma unroll
    for (int off = 32; off >= 1; off >>= 1) acc[e] += __shfl_xor(acc[e], off);
  }
  float mx = acc[0];
#pragma unroll
  for (int e = 1; e < 8; e++) mx = fmaxf(mx, acc[e]);
  float p[8], s = 0.f;
#pragma unroll
  for (int e = 0; e < 8; e++) { p[e] = expf(acc[e] - mx); s += p[e]; }
  float inv = 1.f / s;
#pragma unroll
  for (int e = 0; e < 8; e++) p[e] *= inv;
  int i0 = 0;
#pragma unroll
  for (int e = 1; e < 8; e++) if (p[e] > p[i0]) i0 = e;
  int i1 = (i0 == 0) ? 1 : 0;
#pragma unroll
  for (int e = 0; e < 8; e++) if (e != i0 && p[e] > p[i1]) i1 = e;
  float wsum = p[i0] + p[i1];

  __shared__ float sP[4][8];
  if (lane == 0) {
    expert_sel[tok * 2] = i0;
    expert_sel[tok * 2 + 1] = i1;
    slot_w[tok * 2] = p[i0] / wsum;
    slot_w[tok * 2 + 1] = p[i1] / wsum;
#pragma unroll
    for (int e = 0; e < 8; e++) sP[wave][e] = p[e];
  }
  __syncthreads();
  if (threadIdx.x < 8)
    Pbuf[threadIdx.x * 2048 + blockIdx.x] =
        sP[0][threadIdx.x] + sP[1][threadIdx.x] + sP[2][threadIdx.x] + sP[3][threadIdx.x];
}

// ---------------- offsets: histogram + tile lists + aux loss ----------------
__global__ __launch_bounds__(256) void offsets_kernel(const int* __restrict__ expert_sel,
                                                      int* __restrict__ meta,
                                                      const float* __restrict__ Pbuf,
                                                      float* __restrict__ aux_out) {
  int t = threadIdx.x;
  // histogram of expert_sel (16384 entries), 16-bit packed lanes
  unsigned long long pA = 0, pB = 0;
  for (int i = 0; i < 64; i++) {
    int e = expert_sel[i * 256 + t];
    if (e < 4) pA += 1ull << (e * 16);
    else       pB += 1ull << ((e - 4) * 16);
  }
#pragma unroll
  for (int off = 32; off >= 1; off >>= 1) {
    pA += __shfl_xor(pA, off);
    pB += __shfl_xor(pB, off);
  }
  __shared__ unsigned long long sA[4], sB[4];
  __shared__ float red[8][33];
  int wave = t >> 6, lane = t & 63;
  if (lane == 0) { sA[wave] = pA; sB[wave] = pB; }
  // Pbuf partial reduction
  int ee = t >> 5, j = t & 31;
  float s = 0.f;
  for (int c = j; c < 2048; c += 32) s += Pbuf[ee * 2048 + c];
  red[ee][j] = s;
  __syncthreads();
  if (t == 0) {
    unsigned long long A = sA[0] + sA[1] + sA[2] + sA[3];
    unsigned long long B = sB[0] + sB[1] + sB[2] + sB[3];
    int cnt[8];
    for (int e = 0; e < 4; e++) cnt[e] = (int)((A >> (e * 16)) & 0xFFFF);
    for (int e = 0; e < 4; e++) cnt[4 + e] = (int)((B >> (e * 16)) & 0xFFFF);
    float psum[8];
    for (int e = 0; e < 8; e++) {
      float ss = 0.f;
      for (int k = 0; k < 32; k++) ss += red[e][k];
      psum[e] = ss;
    }
    int off = 0, n1 = 0, n2 = 0;
    float aux = 0.f;
    for (int e = 0; e < 8; e++) {
      int c = cnt[e];
      meta[MI_POS + e] = off;
      int t1 = (c + 255) >> 8;
      for (int jj = 0; jj < t1; jj++) { meta[MI_MTE1 + n1] = e; meta[MI_MTB1 + n1] = off + jj * 256; n1++; }
      int t2 = (c + 127) >> 7;
      for (int jj = 0; jj < t2; jj++) { meta[MI_MTE2 + n2] = e; meta[MI_MTB2 + n2] = off + jj * 128; n2++; }
      off += t1 * 256;
      aux += ((float)c / 16384.f) * (psum[e] / 8192.f);
    }
    meta[MI_T1] = n1;
    meta[MI_T2] = n2;
    *aux_out = 8.f * aux;
  }
}

// ---------------- assign: ballot-aggregated positions ----------------
__global__ __launch_bounds__(256) void assign_kernel(const int* __restrict__ expert_sel,
                                                     int* __restrict__ meta,
                                                     int* __restrict__ slot_pos) {
  int tid = threadIdx.x, wave = tid >> 6, lane = tid & 63;
  int slot = blockIdx.x * 256 + tid;
  int e = expert_sel[slot];
  __shared__ int cnt[4][8];
  __shared__ int base[8];
  __shared__ int woff[4][8];
  int rank = 0;
#pragma unroll
  for (int ee = 0; ee < 8; ee++) {
    unsigned long long msk = __ballot(e == ee);
    if (lane == 0) cnt[wave][ee] = __popcll(msk);
    if (e == ee) rank = __popcll(msk & ((1ull << lane) - 1ull));
  }
  __syncthreads();
  if (tid < 8) {
    int c0 = cnt[0][tid], c1 = cnt[1][tid], c2 = cnt[2][tid], c3 = cnt[3][tid];
    int tot = c0 + c1 + c2 + c3;
    base[tid] = atomicAdd(&meta[MI_POS + tid], tot);
    woff[0][tid] = 0; woff[1][tid] = c0; woff[2][tid] = c0 + c1; woff[3][tid] = c0 + c1 + c2;
  }
  __syncthreads();
  slot_pos[slot] = base[e] + woff[wave][e] + rank;
}

// ---------------- gather: one read per token, write both slots ----------------
__global__ __launch_bounds__(256) void gather_kernel(const int* __restrict__ slot_pos,
                                                     const float* __restrict__ x,
                                                     __hip_bfloat16* __restrict__ Xg) {
  int wave = threadIdx.x >> 6, lane = threadIdx.x & 63;
  int tok = blockIdx.x * 4 + wave;
  int p0 = slot_pos[tok * 2], p1 = slot_pos[tok * 2 + 1];
  const float4* src = (const float4*)(x + (size_t)tok * D_DIM);
  __hip_bfloat16* d0 = Xg + (size_t)p0 * D_DIM;
  __hip_bfloat16* d1 = Xg + (size_t)p1 * D_DIM;
#pragma unroll
  for (int p = 0; p < 4; p++) {
    float4 v = src[p * 64 + lane];
    union { ushort4 u4; __hip_bfloat16 h[4]; } cv;
    cv.h[0] = __float2bfloat16(v.x);
    cv.h[1] = __float2bfloat16(v.y);
    cv.h[2] = __float2bfloat16(v.z);
    cv.h[3] = __float2bfloat16(v.w);
    *(ushort4*)(d0 + (p * 64 + lane) * 4) = cv.u4;
    *(ushort4*)(d1 + (p * 64 + lane) * 4) = cv.u4;
  }
}

// ---------------- GEMM helpers (BK=64) ----------------
// LDS tile rows of 128B; 16B granule g (0..7) XOR-swizzled with row&7.
__device__ __forceinline__ short8 frag_read64(const char* tile, int row, int gk) {
  int byte = (row << 7) | ((gk ^ (row & 7)) << 4);
  return *(const short8*)(tile + byte);
}

// stage NITER*4096 bytes (BLK threads x 16B) of [rows][64] bf16 tile
template <int NITER, int BLK>
__device__ __forceinline__ void stage_rowsT(const __hip_bfloat16* gbase, int ld, char* tile,
                                            int tid) {
#pragma unroll
  for (int i = 0; i < NITER; i++) {
    int L = i * (BLK * 16) + tid * 16;
    int row = L >> 7;
    int g = (L >> 4) & 7;
    int gs = g ^ (row & 7);  // pre-swizzled global source, linear LDS dest
    const char* src = (const char*)(gbase + (size_t)row * ld) + gs * 16;
    GLD16(src, tile + i * (BLK * 16) + (tid >> 6) * 1024);
  }
}

// bijective XCD-chunked swizzle; m fastest within chunk (nwg % 8 == 0)
__device__ __forceinline__ void tile_from_bid(int bid, int nwg, int mmax, int* m, int* n) {
  int cpx = nwg >> 3;
  int u = (bid & 7) * cpx + (bid >> 3);
  *n = u / mmax;
  *m = u % mmax;
}

// ---------------- GEMM1: Hb = silu/fuse( Xg @ w13t^T ), 256x(256 interleaved) ----------------
__global__ __launch_bounds__(512, 1) void gemm1_kernel(const __hip_bfloat16* __restrict__ Xg,
                                                       const __hip_bfloat16* __restrict__ w13t,
                                                       __hip_bfloat16* __restrict__ Hb,
                                                       const int* __restrict__ meta) {
  int m, nIdx;
  tile_from_bid(blockIdx.x, (2 * H_DIM / 256) * MT1_MAX, MT1_MAX, &m, &nIdx);
  if (m >= meta[MI_T1]) return;
  int e = meta[MI_MTE1 + m];
  int row0 = meta[MI_MTB1 + m];
  int n0 = nIdx * 256;
  __shared__ __align__(16) char ldsA[32768];
  __shared__ __align__(16) char ldsB[32768];
  int tid = threadIdx.x, wid = tid >> 6, lane = tid & 63;
  int wr = wid >> 1, wc = wid & 1;  // 4 M-subtiles x 2 B-subtiles
  const __hip_bfloat16* Ab = Xg + (size_t)row0 * D_DIM;
  const __hip_bfloat16* Bb = w13t + ((size_t)e * (2 * H_DIM) + n0) * D_DIM;

  f32x4 acc[4][8];
#pragma unroll
  for (int i = 0; i < 4; i++)
#pragma unroll
    for (int j = 0; j < 8; j++) acc[i][j] = 0.f;

  int rsel = lane & 15, kg = lane >> 4;
  for (int k0 = 0; k0 < D_DIM; k0 += 64) {
    stage_rowsT<4, 512>(Ab + k0, D_DIM, ldsA, tid);
    stage_rowsT<4, 512>(Bb + k0, D_DIM, ldsB, tid);
    asm volatile("s_waitcnt vmcnt(0)" ::: "memory");
    __syncthreads();
#pragma unroll
    for (int kk = 0; kk < 2; kk++) {
      int gk = kk * 4 + kg;
      short8 a[4], b[8];
#pragma unroll
      for (int f = 0; f < 4; f++) a[f] = frag_read64(ldsA, wr * 64 + f * 16 + rsel, gk);
#pragma unroll
      for (int f = 0; f < 8; f++) b[f] = frag_read64(ldsB, wc * 128 + f * 16 + rsel, gk);
#pragma unroll
      for (int fm = 0; fm < 4; fm++)
#pragma unroll
        for (int fn = 0; fn < 8; fn++)
          acc[fm][fn] = __builtin_amdgcn_mfma_f32_16x16x32_bf16(a[fm], b[fn], acc[fm][fn], 0, 0, 0);
    }
    __syncthreads();
  }
  int rq = lane >> 4;
#pragma unroll
  for (int fm = 0; fm < 4; fm++)
#pragma unroll
    for (int fnp = 0; fnp < 4; fnp++)
#pragma unroll
      for (int j = 0; j < 4; j++) {
        float v1 = acc[fm][2 * fnp][j], v3 = acc[fm][2 * fnp + 1][j];
        float h = (v1 / (1.f + expf(-v1))) * v3;  // silu(v1)*v3
        int r = row0 + wr * 64 + fm * 16 + rq * 4 + j;
        int c = (n0 >> 1) + wc * 64 + fnp * 16 + rsel;
        Hb[(size_t)r * H_DIM + c] = __float2bfloat16(h);
      }
}

// ---------------- GEMM2: Y = Hb @ w2t^T (bf16 out), 128x256 tile ----------------
__global__ __launch_bounds__(256, 2) void gemm2_kernel(const __hip_bfloat16* __restrict__ Hb,
                                                       const __hip_bfloat16* __restrict__ w2t,
                                                       __hip_bfloat16* __restrict__ Y,
                                                       const int* __restrict__ meta) {
  int m, nIdx;
  tile_from_bid(blockIdx.x, (D_DIM / 256) * MT2_MAX, MT2_MAX, &m, &nIdx);
  if (m >= meta[MI_T2]) return;
  int e = meta[MI_MTE2 + m];
  int row0 = meta[MI_MTB2 + m];
  int n0 = nIdx * 256;
  __shared__ __align__(16) char ldsA[16384];
  __shared__ __align__(16) char ldsB[32768];
  int tid = threadIdx.x, wave = tid >> 6, lane = tid & 63;
  int wr = wave >> 1, wc = wave & 1;
  const __hip_bfloat16* Ab = Hb + (size_t)row0 * H_DIM;
  const __hip_bfloat16* Bb = w2t + ((size_t)e * D_DIM + n0) * H_DIM;

  f32x4 acc[4][8];
#pragma unroll
  for (int i = 0; i < 4; i++)
#pragma unroll
    for (int j = 0; j < 8; j++) acc[i][j] = 0.f;

  int rsel = lane & 15, kg = lane >> 4;
  for (int k0 = 0; k0 < H_DIM; k0 += 64) {
    stage_rowsT<4, 256>(Ab + k0, H_DIM, ldsA, tid);
    stage_rowsT<8, 256>(Bb + k0, H_DIM, ldsB, tid);
    asm volatile("s_waitcnt vmcnt(0)" ::: "memory");
    __syncthreads();
#pragma unroll
    for (int kk = 0; kk < 2; kk++) {
      int gk = kk * 4 + kg;
      short8 a[4], b[8];
#pragma unroll
      for (int f = 0; f < 4; f++) a[f] = frag_read64(ldsA, wr * 64 + f * 16 + rsel, gk);
#pragma unroll
      for (int f = 0; f < 8; f++) b[f] = frag_read64(ldsB, wc * 128 + f * 16 + rsel, gk);
#pragma unroll
      for (int fm = 0; fm < 4; fm++)
#pragma unroll
        for (int fn = 0; fn < 8; fn++)
          acc[fm][fn] = __builtin_amdgcn_mfma_f32_16x16x32_bf16(a[fm], b[fn], acc[fm][fn], 0, 0, 0);
    }
    __syncthreads();
  }
  int rq = lane >> 4;
#pragma unroll
  for (int fm = 0; fm < 4; fm++)
#pragma unroll
    for (int fn = 0; fn < 8; fn++)
#pragma unroll
      for (int j = 0; j < 4; j++) {
        int r = row0 + wr * 64 + fm * 16 + rq * 4 + j;
        int c = n0 + wc * 128 + fn * 16 + rsel;
        Y[(size_t)r * D_DIM + c] = __float2bfloat16(acc[fm][fn][j]);
      }
}

// ---------------- combine: out[t] = w0*Y[p0] + w1*Y[p1] (bf16 Y) ----------------
__global__ __launch_bounds__(256) void combine_kernel(const int* __restrict__ slot_pos,
                                                      const float* __restrict__ slot_w,
                                                      const __hip_bfloat16* __restrict__ Y,
                                                      float* __restrict__ outp) {
  int tok = blockIdx.x;
  int p0 = slot_pos[tok * 2], p1 = slot_pos[tok * 2 + 1];
  float w0 = slot_w[tok * 2], w1 = slot_w[tok * 2 + 1];
  int i4 = threadIdx.x;  // 256 threads x 4 elems
  ushort4 a = *(const ushort4*)(Y + (size_t)p0 * D_DIM + i4 * 4);
  ushort4 b = *(const ushort4*)(Y + (size_t)p1 * D_DIM + i4 * 4);
  union { ushort u; __hip_bfloat16 h; } c0, c1;
  float4 r;
  c0.u = a.x; c1.u = b.x; r.x = w0 * __bfloat162float(c0.h) + w1 * __bfloat162float(c1.h);
  c0.u = a.y; c1.u = b.y; r.y = w0 * __bfloat162float(c0.h) + w1 * __bfloat162float(c1.h);
  c0.u = a.z; c1.u = b.z; r.z = w0 * __bfloat162float(c0.h) + w1 * __bfloat162float(c1.h);
  c0.u = a.w; c1.u = b.w; r.w = w0 * __bfloat162float(c0.h) + w1 * __bfloat162float(c1.h);
  ((float4*)(outp + (size_t)tok * D_DIM))[i4] = r;
}

// ---------------- launch ----------------
extern "C" void kernel_launch(void* const* d_in, const int* in_sizes, int n_in,
                              void* d_out, int out_size, void* d_ws, size_t ws_size,
                              hipStream_t stream) {
  const float* x = (const float*)d_in[0];
  const float* Wr = (const float*)d_in[1];
  const float* w1 = (const float*)d_in[2];
  const float* w3 = (const float*)d_in[3];
  const float* w2 = (const float*)d_in[4];
  float* outp = (float*)d_out;

  char* ws = (char*)d_ws;
  size_t off = 0;
  auto alloc = [&](size_t bytes) -> char* {
    char* p = ws + off;
    off += (bytes + 255) & ~(size_t)255;
    return p;
  };
  __hip_bfloat16* w13t = (__hip_bfloat16*)alloc((size_t)E_EXP * 2 * H_DIM * D_DIM * 2);
  __hip_bfloat16* w2t = (__hip_bfloat16*)alloc((size_t)E_EXP * D_DIM * H_DIM * 2);
  __hip_bfloat16* Xg = (__hip_bfloat16*)alloc((size_t)CAP_ROWS * D_DIM * 2);
  __hip_bfloat16* Hb = (__hip_bfloat16*)alloc((size_t)CAP_ROWS * H_DIM * 2);
  __hip_bfloat16* Y = (__hip_bfloat16*)alloc((size_t)CAP_ROWS * D_DIM * 2);
  float* slot_w = (float*)alloc(NSLOT * 4);
  int* slot_pos = (int*)alloc(NSLOT * 4);
  int* expert_sel = (int*)alloc(NSLOT * 4);
  float* Pbuf = (float*)alloc(2048 * 8 * 4);
  int* meta = (int*)alloc(2048);
  (void)ws_size; (void)in_sizes; (void)n_in; (void)out_size;

  w13_transpose<<<dim3(H_DIM / 64, D_DIM / 64, 2 * E_EXP), dim3(256), 0, stream>>>(w1, w3, w13t);
  transpose_convert<H_DIM, D_DIM><<<dim3(D_DIM / 64, H_DIM / 64, E_EXP), dim3(256), 0, stream>>>(w2, w2t);
  router_kernel<<<dim3(T_TOK / 4), dim3(256), 0, stream>>>(x, Wr, Pbuf, expert_sel, slot_w);
  offsets_kernel<<<dim3(1), dim3(256), 0, stream>>>(expert_sel, meta, Pbuf, outp + (size_t)T_TOK * D_DIM);
  assign_kernel<<<dim3(NSLOT / 256), dim3(256), 0, stream>>>(expert_sel, meta, slot_pos);
  gather_kernel<<<dim3(T_TOK / 4), dim3(256), 0, stream>>>(slot_pos, x, Xg);
  gemm1_kernel<<<dim3((2 * H_DIM / 256) * MT1_MAX), dim3(512), 0, stream>>>(Xg, w13t, Hb, meta);
  gemm2_kernel<<<dim3((D_DIM / 256) * MT2_MAX), dim3(256), 0, stream>>>(Hb, w2t, Y, meta);
  combine_kernel<<<dim3(T_TOK), dim3(256), 0, stream>>>(slot_pos, slot_w, Y, outp);
}

// Round 7
// 556.171 us; speedup vs baseline: 1.3582x; 1.1001x over previous
//
#include <hip/hip_runtime.h>
#include <hip/hip_bf16.h>
#include <stdint.h>

// MoE top-2 (T=8192, D=1024, H=2816, E=8) — sparse grouped-GEMM implementation.
// R7: gemm1 reverted to proven 128-row 2-phase structure (R5, 2 blocks/CU);
// merged single-launch weight transpose; rest as R6 (histogram offsets, dual
// tile lists, BN=256 gemm2 with bf16 Y).

#define T_TOK 8192
#define D_DIM 1024
#define H_DIM 2816
#define E_EXP 8
#define NSLOT 16384       // T * 2
#define CAP_ROWS 18432    // 72 * 256
#define MT1_MAX 72        // 256-row tiles (unused by gemms this round)
#define MT2_MAX 136       // 128-row tiles

// meta int layout
#define MI_T1 0
#define MI_T2 1
#define MI_POS 8
#define MI_MTE1 16
#define MI_MTB1 (16 + MT1_MAX)
#define MI_MTE2 (16 + 2 * MT1_MAX)
#define MI_MTB2 (16 + 2 * MT1_MAX + MT2_MAX)

typedef __attribute__((ext_vector_type(8))) short short8;
typedef __attribute__((ext_vector_type(4))) float f32x4;

#define GLD16(gsrc, ldst) __builtin_amdgcn_global_load_lds( \
    (const __attribute__((address_space(1))) void*)(gsrc),  \
    (__attribute__((address_space(3))) void*)(ldst), 16, 0, 0)

// ---------------- merged weight transpose + f32->bf16 ----------------
// blocks [0, 11264): w13 interleaved transpose, (E,D,H)x2 -> (E,2H,D)
//   z = bid/704 (e = z>>1, w3f = z&1), rem: bx = rem%44 (h0), by = rem/44 (d0)
// blocks [11264, 16896): w2 transpose, (E,H,D) -> (E,D,H)
//   b2 = bid-11264, e = b2/704, rem: bx = rem%16 (c0 over D), by = rem/16 (r0 over H)
__global__ __launch_bounds__(256) void transpose_all(const float* __restrict__ w1,
                                                     const float* __restrict__ w3,
                                                     const float* __restrict__ w2,
                                                     __hip_bfloat16* __restrict__ w13t,
                                                     __hip_bfloat16* __restrict__ w2t) {
  __shared__ float tile[64][65];
  int bid = blockIdx.x, tid = threadIdx.x;
  int lc = (tid & 15) * 4;
  int lr = tid >> 4;
  if (bid < 11264) {
    int z = bid / 704, rem = bid % 704;
    int bx = rem % 44, by = rem / 44;
    int e = z >> 1, w3f = z & 1;
    const float* in = w3f ? w3 : w1;
    int h0 = bx * 64, d0 = by * 64;
    const float* src = in + ((size_t)e * D_DIM + d0) * H_DIM + h0;
#pragma unroll
    for (int i = 0; i < 4; i++) {
      float4 v = *(const float4*)(src + (size_t)(lr + i * 16) * H_DIM + lc);
      tile[lr + i * 16][lc + 0] = v.x;
      tile[lr + i * 16][lc + 1] = v.y;
      tile[lr + i * 16][lc + 2] = v.z;
      tile[lr + i * 16][lc + 3] = v.w;
    }
    __syncthreads();
    __hip_bfloat16* dstE = w13t + (size_t)e * (2 * H_DIM) * D_DIM;
    int rB = (tid & 7) * 8;  // d offset within tile
#pragma unroll
    for (int i = 0; i < 2; i++) {
      int hh = (tid >> 3) + i * 32;
      int habs = h0 + hh;
      int rw = 2 * (habs & ~15) + (habs & 15) + (w3f ? 16 : 0);
      __align__(16) __hip_bfloat16 o[8];
#pragma unroll
      for (int k = 0; k < 8; k++) o[k] = __float2bfloat16(tile[rB + k][hh]);
      *(short8*)(dstE + (size_t)rw * D_DIM + d0 + rB) = *(const short8*)o;
    }
  } else {
    int b2 = bid - 11264;
    int e = b2 / 704, rem = b2 % 704;
    int bx = rem % 16, by = rem / 16;
    int c0 = bx * 64, r0 = by * 64;  // R = H_DIM rows, C = D_DIM cols
    const float* src = w2 + ((size_t)e * H_DIM + r0) * D_DIM + c0;
#pragma unroll
    for (int i = 0; i < 4; i++) {
      float4 v = *(const float4*)(src + (size_t)(lr + i * 16) * D_DIM + lc);
      tile[lr + i * 16][lc + 0] = v.x;
      tile[lr + i * 16][lc + 1] = v.y;
      tile[lr + i * 16][lc + 2] = v.z;
      tile[lr + i * 16][lc + 3] = v.w;
    }
    __syncthreads();
    __hip_bfloat16* dst = w2t + ((size_t)e * D_DIM + c0) * H_DIM + r0;
    int rB = (tid & 7) * 8;
#pragma unroll
    for (int i = 0; i < 2; i++) {
      int c = (tid >> 3) + i * 32;
      __align__(16) __hip_bfloat16 o[8];
#pragma unroll
      for (int k = 0; k < 8; k++) o[k] = __float2bfloat16(tile[rB + k][c]);
      *(short8*)(dst + (size_t)c * H_DIM + rB) = *(const short8*)o;
    }
  }
}

// ---------------- router (no atomics) ----------------
__global__ __launch_bounds__(256) void router_kernel(const float* __restrict__ x,
                                                     const float* __restrict__ Wr,
                                                     float* __restrict__ Pbuf,
                                                     int* __restrict__ expert_sel,
                                                     float* __restrict__ slot_w) {
  int wave = threadIdx.x >> 6, lane = threadIdx.x & 63;
  int tok = blockIdx.x * 4 + wave;
  const float* xr = x + (size_t)tok * D_DIM;
  float acc[8];
#pragma unroll
  for (int e = 0; e < 8; e++) acc[e] = 0.f;
  for (int d = lane; d < D_DIM; d += 64) {
    float xv = xr[d];
    const float4* w4 = (const float4*)(Wr + d * 8);
    float4 wa = w4[0], wb = w4[1];
    acc[0] += xv * wa.x; acc[1] += xv * wa.y; acc[2] += xv * wa.z; acc[3] += xv * wa.w;
    acc[4] += xv * wb.x; acc[5] += xv * wb.y; acc[6] += xv * wb.z; acc[7] += xv * wb.w;
  }
#pragma unroll
  for (int e = 0; e < 8; e++) {
#pragma unroll
    for (int off = 32; off >= 1; off >>= 1) acc[e] += __shfl_xor(acc[e], off);
  }
  float mx = acc[0];
#pragma unroll
  for (int e = 1; e < 8; e++) mx = fmaxf(mx, acc[e]);
  float p[8], s = 0.f;
#pragma unroll
  for (int e = 0; e < 8; e++) { p[e] = expf(acc[e] - mx); s += p[e]; }
  float inv = 1.f / s;
#pragma unroll
  for (int e = 0; e < 8; e++) p[e] *= inv;
  int i0 = 0;
#pragma unroll
  for (int e = 1; e < 8; e++) if (p[e] > p[i0]) i0 = e;
  int i1 = (i0 == 0) ? 1 : 0;
#pragma unroll
  for (int e = 0; e < 8; e++) if (e != i0 && p[e] > p[i1]) i1 = e;
  float wsum = p[i0] + p[i1];

  __shared__ float sP[4][8];
  if (lane == 0) {
    expert_sel[tok * 2] = i0;
    expert_sel[tok * 2 + 1] = i1;
    slot_w[tok * 2] = p[i0] / wsum;
    slot_w[tok * 2 + 1] = p[i1] / wsum;
#pragma unroll
    for (int e = 0; e < 8; e++) sP[wave][e] = p[e];
  }
  __syncthreads();
  if (threadIdx.x < 8)
    Pbuf[threadIdx.x * 2048 + blockIdx.x] =
        sP[0][threadIdx.x] + sP[1][threadIdx.x] + sP[2][threadIdx.x] + sP[3][threadIdx.x];
}

// ---------------- offsets: histogram + tile lists + aux loss ----------------
__global__ __launch_bounds__(256) void offsets_kernel(const int* __restrict__ expert_sel,
                                                      int* __restrict__ meta,
                                                      const float* __restrict__ Pbuf,
                                                      float* __restrict__ aux_out) {
  int t = threadIdx.x;
  // histogram of expert_sel (16384 entries), 16-bit packed lanes
  unsigned long long pA = 0, pB = 0;
  for (int i = 0; i < 64; i++) {
    int e = expert_sel[i * 256 + t];
    if (e < 4) pA += 1ull << (e * 16);
    else       pB += 1ull << ((e - 4) * 16);
  }
#pragma unroll
  for (int off = 32; off >= 1; off >>= 1) {
    pA += __shfl_xor(pA, off);
    pB += __shfl_xor(pB, off);
  }
  __shared__ unsigned long long sA[4], sB[4];
  __shared__ float red[8][33];
  int wave = t >> 6, lane = t & 63;
  if (lane == 0) { sA[wave] = pA; sB[wave] = pB; }
  // Pbuf partial reduction
  int ee = t >> 5, j = t & 31;
  float s = 0.f;
  for (int c = j; c < 2048; c += 32) s += Pbuf[ee * 2048 + c];
  red[ee][j] = s;
  __syncthreads();
  if (t == 0) {
    unsigned long long A = sA[0] + sA[1] + sA[2] + sA[3];
    unsigned long long B = sB[0] + sB[1] + sB[2] + sB[3];
    int cnt[8];
    for (int e = 0; e < 4; e++) cnt[e] = (int)((A >> (e * 16)) & 0xFFFF);
    for (int e = 0; e < 4; e++) cnt[4 + e] = (int)((B >> (e * 16)) & 0xFFFF);
    float psum[8];
    for (int e = 0; e < 8; e++) {
      float ss = 0.f;
      for (int k = 0; k < 32; k++) ss += red[e][k];
      psum[e] = ss;
    }
    int off = 0, n1 = 0, n2 = 0;
    float aux = 0.f;
    for (int e = 0; e < 8; e++) {
      int c = cnt[e];
      meta[MI_POS + e] = off;
      int t1 = (c + 255) >> 8;
      for (int jj = 0; jj < t1; jj++) { meta[MI_MTE1 + n1] = e; meta[MI_MTB1 + n1] = off + jj * 256; n1++; }
      int t2 = (c + 127) >> 7;
      for (int jj = 0; jj < t2; jj++) { meta[MI_MTE2 + n2] = e; meta[MI_MTB2 + n2] = off + jj * 128; n2++; }
      off += t1 * 256;
      aux += ((float)c / 16384.f) * (psum[e] / 8192.f);
    }
    meta[MI_T1] = n1;
    meta[MI_T2] = n2;
    *aux_out = 8.f * aux;
  }
}

// ---------------- assign: ballot-aggregated positions ----------------
__global__ __launch_bounds__(256) void assign_kernel(const int* __restrict__ expert_sel,
                                                     int* __restrict__ meta,
                                                     int* __restrict__ slot_pos) {
  int tid = threadIdx.x, wave = tid >> 6, lane = tid & 63;
  int slot = blockIdx.x * 256 + tid;
  int e = expert_sel[slot];
  __shared__ int cnt[4][8];
  __shared__ int base[8];
  __shared__ int woff[4][8];
  int rank = 0;
#pragma unroll
  for (int ee = 0; ee < 8; ee++) {
    unsigned long long msk = __ballot(e == ee);
    if (lane == 0) cnt[wave][ee] = __popcll(msk);
    if (e == ee) rank = __popcll(msk & ((1ull << lane) - 1ull));
  }
  __syncthreads();
  if (tid < 8) {
    int c0 = cnt[0][tid], c1 = cnt[1][tid], c2 = cnt[2][tid], c3 = cnt[3][tid];
    int tot = c0 + c1 + c2 + c3;
    base[tid] = atomicAdd(&meta[MI_POS + tid], tot);
    woff[0][tid] = 0; woff[1][tid] = c0; woff[2][tid] = c0 + c1; woff[3][tid] = c0 + c1 + c2;
  }
  __syncthreads();
  slot_pos[slot] = base[e] + woff[wave][e] + rank;
}

// ---------------- gather: one read per token, write both slots ----------------
__global__ __launch_bounds__(256) void gather_kernel(const int* __restrict__ slot_pos,
                                                     const float* __restrict__ x,
                                                     __hip_bfloat16* __restrict__ Xg) {
  int wave = threadIdx.x >> 6, lane = threadIdx.x & 63;
  int tok = blockIdx.x * 4 + wave;
  int p0 = slot_pos[tok * 2], p1 = slot_pos[tok * 2 + 1];
  const float4* src = (const float4*)(x + (size_t)tok * D_DIM);
  __hip_bfloat16* d0 = Xg + (size_t)p0 * D_DIM;
  __hip_bfloat16* d1 = Xg + (size_t)p1 * D_DIM;
#pragma unroll
  for (int p = 0; p < 4; p++) {
    float4 v = src[p * 64 + lane];
    union { ushort4 u4; __hip_bfloat16 h[4]; } cv;
    cv.h[0] = __float2bfloat16(v.x);
    cv.h[1] = __float2bfloat16(v.y);
    cv.h[2] = __float2bfloat16(v.z);
    cv.h[3] = __float2bfloat16(v.w);
    *(ushort4*)(d0 + (p * 64 + lane) * 4) = cv.u4;
    *(ushort4*)(d1 + (p * 64 + lane) * 4) = cv.u4;
  }
}

// ---------------- GEMM helpers (BK=64) ----------------
// LDS tile rows of 128B; 16B granule g (0..7) XOR-swizzled with row&7.
__device__ __forceinline__ short8 frag_read64(const char* tile, int row, int gk) {
  int byte = (row << 7) | ((gk ^ (row & 7)) << 4);
  return *(const short8*)(tile + byte);
}

// stage NITER*(BLK*16) bytes of [rows][64] bf16 tile
template <int NITER, int BLK>
__device__ __forceinline__ void stage_rowsT(const __hip_bfloat16* gbase, int ld, char* tile,
                                            int tid) {
#pragma unroll
  for (int i = 0; i < NITER; i++) {
    int L = i * (BLK * 16) + tid * 16;
    int row = L >> 7;
    int g = (L >> 4) & 7;
    int gs = g ^ (row & 7);  // pre-swizzled global source, linear LDS dest
    const char* src = (const char*)(gbase + (size_t)row * ld) + gs * 16;
    GLD16(src, tile + i * (BLK * 16) + (tid >> 6) * 1024);
  }
}

// bijective XCD-chunked swizzle; m fastest within chunk (nwg % 8 == 0)
__device__ __forceinline__ void tile_from_bid(int bid, int nwg, int mmax, int* m, int* n) {
  int cpx = nwg >> 3;
  int u = (bid & 7) * cpx + (bid >> 3);
  *n = u / mmax;
  *m = u % mmax;
}

// ---------------- GEMM1: Hb = silu/fuse( Xg @ w13t^T ), 128x(256 interleaved) ----------------
__global__ __launch_bounds__(256, 2) void gemm1_kernel(const __hip_bfloat16* __restrict__ Xg,
                                                       const __hip_bfloat16* __restrict__ w13t,
                                                       __hip_bfloat16* __restrict__ Hb,
                                                       const int* __restrict__ meta) {
  int m, nIdx;
  tile_from_bid(blockIdx.x, (2 * H_DIM / 256) * MT2_MAX, MT2_MAX, &m, &nIdx);
  if (m >= meta[MI_T2]) return;
  int e = meta[MI_MTE2 + m];
  int row0 = meta[MI_MTB2 + m];
  int n0 = nIdx * 256;
  __shared__ __align__(16) char ldsA[16384];
  __shared__ __align__(16) char ldsB[32768];
  int tid = threadIdx.x, wave = tid >> 6, lane = tid & 63;
  int wr = wave >> 1, wc = wave & 1;
  const __hip_bfloat16* Ab = Xg + (size_t)row0 * D_DIM;
  const __hip_bfloat16* Bb = w13t + ((size_t)e * (2 * H_DIM) + n0) * D_DIM;

  f32x4 acc[4][8];
#pragma unroll
  for (int i = 0; i < 4; i++)
#pragma unroll
    for (int j = 0; j < 8; j++) acc[i][j] = 0.f;

  int rsel = lane & 15, kg = lane >> 4;
  for (int k0 = 0; k0 < D_DIM; k0 += 64) {
    stage_rowsT<4, 256>(Ab + k0, D_DIM, ldsA, tid);
    stage_rowsT<8, 256>(Bb + k0, D_DIM, ldsB, tid);
    asm volatile("s_waitcnt vmcnt(0)" ::: "memory");
    __syncthreads();
#pragma unroll
    for (int kk = 0; kk < 2; kk++) {
      int gk = kk * 4 + kg;
      short8 a[4], b[8];
#pragma unroll
      for (int f = 0; f < 4; f++) a[f] = frag_read64(ldsA, wr * 64 + f * 16 + rsel, gk);
#pragma unroll
      for (int f = 0; f < 8; f++) b[f] = frag_read64(ldsB, wc * 128 + f * 16 + rsel, gk);
#pragma unroll
      for (int fm = 0; fm < 4; fm++)
#pragma unroll
        for (int fn = 0; fn < 8; fn++)
          acc[fm][fn] = __builtin_amdgcn_mfma_f32_16x16x32_bf16(a[fm], b[fn], acc[fm][fn], 0, 0, 0);
    }
    __syncthreads();
  }
  int rq = lane >> 4;
#pragma unroll
  for (int fm = 0; fm < 4; fm++)
#pragma unroll
    for (int fnp = 0; fnp < 4; fnp++)
#pragma unroll
      for (int j = 0; j < 4; j++) {
        float v1 = acc[fm][2 * fnp][j], v3 = acc[fm][2 * fnp + 1][j];
        float h = (v1 / (1.f + expf(-v1))) * v3;  // silu(v1)*v3
        int r = row0 + wr * 64 + fm * 16 + rq * 4 + j;
        int c = (n0 >> 1) + wc * 64 + fnp * 16 + rsel;
        Hb[(size_t)r * H_DIM + c] = __float2bfloat16(h);
      }
}

// ---------------- GEMM2: Y = Hb @ w2t^T (bf16 out), 128x256 tile ----------------
__global__ __launch_bounds__(256, 2) void gemm2_kernel(const __hip_bfloat16* __restrict__ Hb,
                                                       const __hip_bfloat16* __restrict__ w2t,
                                                       __hip_bfloat16* __restrict__ Y,
                                                       const int* __restrict__ meta) {
  int m, nIdx;
  tile_from_bid(blockIdx.x, (D_DIM / 256) * MT2_MAX, MT2_MAX, &m, &nIdx);
  if (m >= meta[MI_T2]) return;
  int e = meta[MI_MTE2 + m];
  int row0 = meta[MI_MTB2 + m];
  int n0 = nIdx * 256;
  __shared__ __align__(16) char ldsA[16384];
  __shared__ __align__(16) char ldsB[32768];
  int tid = threadIdx.x, wave = tid >> 6, lane = tid & 63;
  int wr = wave >> 1, wc = wave & 1;
  const __hip_bfloat16* Ab = Hb + (size_t)row0 * H_DIM;
  const __hip_bfloat16* Bb = w2t + ((size_t)e * D_DIM + n0) * H_DIM;

  f32x4 acc[4][8];
#pragma unroll
  for (int i = 0; i < 4; i++)
#pragma unroll
    for (int j = 0; j < 8; j++) acc[i][j] = 0.f;

  int rsel = lane & 15, kg = lane >> 4;
  for (int k0 = 0; k0 < H_DIM; k0 += 64) {
    stage_rowsT<4, 256>(Ab + k0, H_DIM, ldsA, tid);
    stage_rowsT<8, 256>(Bb + k0, H_DIM, ldsB, tid);
    asm volatile("s_waitcnt vmcnt(0)" ::: "memory");
    __syncthreads();
#pragma unroll
    for (int kk = 0; kk < 2; kk++) {
      int gk = kk * 4 + kg;
      short8 a[4], b[8];
#pragma unroll
      for (int f = 0; f < 4; f++) a[f] = frag_read64(ldsA, wr * 64 + f * 16 + rsel, gk);
#pragma unroll
      for (int f = 0; f < 8; f++) b[f] = frag_read64(ldsB, wc * 128 + f * 16 + rsel, gk);
#pragma unroll
      for (int fm = 0; fm < 4; fm++)
#pragma unroll
        for (int fn = 0; fn < 8; fn++)
          acc[fm][fn] = __builtin_amdgcn_mfma_f32_16x16x32_bf16(a[fm], b[fn], acc[fm][fn], 0, 0, 0);
    }
    __syncthreads();
  }
  int rq = lane >> 4;
#pragma unroll
  for (int fm = 0; fm < 4; fm++)
#pragma unroll
    for (int fn = 0; fn < 8; fn++)
#pragma unroll
      for (int j = 0; j < 4; j++) {
        int r = row0 + wr * 64 + fm * 16 + rq * 4 + j;
        int c = n0 + wc * 128 + fn * 16 + rsel;
        Y[(size_t)r * D_DIM + c] = __float2bfloat16(acc[fm][fn][j]);
      }
}

// ---------------- combine: out[t] = w0*Y[p0] + w1*Y[p1] (bf16 Y) ----------------
__global__ __launch_bounds__(256) void combine_kernel(const int* __restrict__ slot_pos,
                                                      const float* __restrict__ slot_w,
                                                      const __hip_bfloat16* __restrict__ Y,
                                                      float* __restrict__ outp) {
  int tok = blockIdx.x;
  int p0 = slot_pos[tok * 2], p1 = slot_pos[tok * 2 + 1];
  float w0 = slot_w[tok * 2], w1 = slot_w[tok * 2 + 1];
  int i4 = threadIdx.x;  // 256 threads x 4 elems
  ushort4 a = *(const ushort4*)(Y + (size_t)p0 * D_DIM + i4 * 4);
  ushort4 b = *(const ushort4*)(Y + (size_t)p1 * D_DIM + i4 * 4);
  union { ushort u; __hip_bfloat16 h; } c0, c1;
  float4 r;
  c0.u = a.x; c1.u = b.x; r.x = w0 * __bfloat162float(c0.h) + w1 * __bfloat162float(c1.h);
  c0.u = a.y; c1.u = b.y; r.y = w0 * __bfloat162float(c0.h) + w1 * __bfloat162float(c1.h);
  c0.u = a.z; c1.u = b.z; r.z = w0 * __bfloat162float(c0.h) + w1 * __bfloat162float(c1.h);
  c0.u = a.w; c1.u = b.w; r.w = w0 * __bfloat162float(c0.h) + w1 * __bfloat162float(c1.h);
  ((float4*)(outp + (size_t)tok * D_DIM))[i4] = r;
}

// ---------------- launch ----------------
extern "C" void kernel_launch(void* const* d_in, const int* in_sizes, int n_in,
                              void* d_out, int out_size, void* d_ws, size_t ws_size,
                              hipStream_t stream) {
  const float* x = (const float*)d_in[0];
  const float* Wr = (const float*)d_in[1];
  const float* w1 = (const float*)d_in[2];
  const float* w3 = (const float*)d_in[3];
  const float* w2 = (const float*)d_in[4];
  float* outp = (float*)d_out;

  char* ws = (char*)d_ws;
  size_t off = 0;
  auto alloc = [&](size_t bytes) -> char* {
    char* p = ws + off;
    off += (bytes + 255) & ~(size_t)255;
    return p;
  };
  __hip_bfloat16* w13t = (__hip_bfloat16*)alloc((size_t)E_EXP * 2 * H_DIM * D_DIM * 2);
  __hip_bfloat16* w2t = (__hip_bfloat16*)alloc((size_t)E_EXP * D_DIM * H_DIM * 2);
  __hip_bfloat16* Xg = (__hip_bfloat16*)alloc((size_t)CAP_ROWS * D_DIM * 2);
  __hip_bfloat16* Hb = (__hip_bfloat16*)alloc((size_t)CAP_ROWS * H_DIM * 2);
  __hip_bfloat16* Y = (__hip_bfloat16*)alloc((size_t)CAP_ROWS * D_DIM * 2);
  float* slot_w = (float*)alloc(NSLOT * 4);
  int* slot_pos = (int*)alloc(NSLOT * 4);
  int* expert_sel = (int*)alloc(NSLOT * 4);
  float* Pbuf = (float*)alloc(2048 * 8 * 4);
  int* meta = (int*)alloc(2048);
  (void)ws_size; (void)in_sizes; (void)n_in; (void)out_size;

  transpose_all<<<dim3(16896), dim3(256), 0, stream>>>(w1, w3, w2, w13t, w2t);
  router_kernel<<<dim3(T_TOK / 4), dim3(256), 0, stream>>>(x, Wr, Pbuf, expert_sel, slot_w);
  offsets_kernel<<<dim3(1), dim3(256), 0, stream>>>(expert_sel, meta, Pbuf, outp + (size_t)T_TOK * D_DIM);
  assign_kernel<<<dim3(NSLOT / 256), dim3(256), 0, stream>>>(expert_sel, meta, slot_pos);
  gather_kernel<<<dim3(T_TOK / 4), dim3(256), 0, stream>>>(slot_pos, x, Xg);
  gemm1_kernel<<<dim3((2 * H_DIM / 256) * MT2_MAX), dim3(256), 0, stream>>>(Xg, w13t, Hb, meta);
  gemm2_kernel<<<dim3((D_DIM / 256) * MT2_MAX), dim3(256), 0, stream>>>(Hb, w2t, Y, meta);
  combine_kernel<<<dim3(T_TOK), dim3(256), 0, stream>>>(slot_pos, slot_w, Y, outp);
}